// Round 11
// baseline (241.423 us; speedup 1.0000x reference)
//
#include <hip/hip_runtime.h>

#define IN_DIM 128
#define HID 64
#define MAXC 400            // >= ceil(N/256); N=100000 -> 391 coarse buckets
#define MAXB 512            // >= NBLK = ceil(E/EPB) = 391
#define EPB 4096
#define DPT 512             // degplace threads per block
#define G1CAP 6144          // LDS floats for k_gather1 staging (E[block]=4096, +32 sigma)

// ---- bf16 helpers (RNE) ----
static __device__ __forceinline__ unsigned short f2bf(float f) {
    unsigned u = __float_as_uint(f);
    u += 0x7FFF + ((u >> 16) & 1);
    return (unsigned short)(u >> 16);
}

typedef short bf16x8 __attribute__((ext_vector_type(8)));
typedef float f32x4 __attribute__((ext_vector_type(4)));

// ---- pass 0: per-block bucket histogram -> hmat[blk][cb]; blk0 zeroes ctr ----
// Blocks 0/1 additionally pre-convert W1/W2 to bf16 [n][k] tables (one-time,
// replaces per-block LDS weight staging in k_mmx / k_gmx).
__global__ __launch_bounds__(256) void k_hist2(const int* __restrict__ dst,
                                               int* __restrict__ hmat,
                                               int* __restrict__ ctr,
                                               const float* __restrict__ W1,
                                               const float* __restrict__ W2,
                                               unsigned short* __restrict__ Wb1,
                                               unsigned short* __restrict__ Wb2,
                                               int E, int NC) {
    __shared__ int h[MAXC];
    int tid = threadIdx.x, blk = blockIdx.x;
    if (blk == 0 && tid == 0) ctr[0] = 0;
    if (blk == 0) {
        for (int i = tid; i < IN_DIM * HID; i += 256) {   // W1[k][n] -> Wb1[n][k]
            int k = i >> 6, n = i & 63;
            Wb1[n * IN_DIM + k] = f2bf(W1[i]);
        }
    } else if (blk == 1) {
        for (int i = tid; i < HID * HID; i += 256) {      // W2[k][n] -> Wb2[n][k]
            int k = i >> 6, n = i & 63;
            Wb2[n * HID + k] = f2bf(W2[i]);
        }
    }
    for (int i = tid; i < NC; i += 256) h[i] = 0;
    __syncthreads();
    int e0 = blk * EPB, e1 = min(e0 + EPB, E);
    for (int e = e0 + tid; e < e1; e += 256) atomicAdd(&h[dst[e] >> 8], 1);
    __syncthreads();
    for (int i = tid; i < NC; i += 256) hmat[blk * MAXC + i] = h[i];
}

// ---- per-bucket exclusive scan across blocks + (last block) bucket-total scan ----
// Cross-block comms via device-scope atomics only (coherence point), per G16.
__global__ __launch_bounds__(512) void k_bktscan(int* __restrict__ hmat,
                                                 int* __restrict__ bktTotal,
                                                 int* __restrict__ ctr,
                                                 int* __restrict__ coarseStart,
                                                 int* __restrict__ rowStart,
                                                 int NBLK, int NC, int N, int E) {
    __shared__ int tmp[512];
    __shared__ int lastFlag;
    int cb = blockIdx.x;
    int t = threadIdx.x;
    int v = (t < NBLK) ? hmat[t * MAXC + cb] : 0;
    tmp[t] = v;
    __syncthreads();
    for (int off = 1; off < 512; off <<= 1) {
        int a = (t >= off) ? tmp[t - off] : 0;
        __syncthreads();
        tmp[t] += a;
        __syncthreads();
    }
    if (t < NBLK) hmat[t * MAXC + cb] = tmp[t] - v;   // exclusive prefix within bucket
    if (t == 511) atomicExch(&bktTotal[cb], tmp[511]); // coherence-point publish
    __syncthreads();                                   // drains the atomic (vmcnt)
    if (t == 0) lastFlag = (atomicAdd(ctr, 1) == (int)gridDim.x - 1);
    __syncthreads();
    if (!lastFlag) return;
    // last arriving block: scan bucket totals -> coarseStart
    int v2 = (t < NC) ? atomicAdd(&bktTotal[t], 0) : 0;  // coherence-point read
    tmp[t] = v2;
    __syncthreads();
    for (int off = 1; off < 512; off <<= 1) {
        int a = (t >= off) ? tmp[t - off] : 0;
        __syncthreads();
        tmp[t] += a;
        __syncthreads();
    }
    int excl = tmp[t] - v2;
    if (t < NC) coarseStart[t] = excl;
    if (t == NC - 1) coarseStart[NC] = excl + v2;   // == E
    if (t == 0) rowStart[N] = E;
}

// ---- pass 1: deterministic placement into dense coarse-sorted array ----
__global__ __launch_bounds__(256) void k_part1(const int* __restrict__ src,
                                               const int* __restrict__ dst,
                                               const int* __restrict__ hmat,
                                               const int* __restrict__ coarseStart,
                                               int* __restrict__ tmp1,
                                               int E, int NC) {
    __shared__ int bcnt[MAXC];
    __shared__ int bbase[MAXC];
    int tid = threadIdx.x, blk = blockIdx.x;
    for (int i = tid; i < NC; i += 256) {
        bcnt[i] = 0;
        bbase[i] = coarseStart[i] + hmat[blk * MAXC + i];   // coalesced
    }
    __syncthreads();
    int e0 = blk * EPB, e1 = min(e0 + EPB, E);
    for (int e = e0 + tid; e < e1; e += 256) {
        int s = src[e], d = dst[e];
        int cb = d >> 8;
        int slot = bbase[cb] + atomicAdd(&bcnt[cb], 1);
        tmp1[slot] = s | ((d & 255) << 17);
    }
}

// ---- pass 2 (fused): per-bucket degree->dis/rowStart, then place into CSR ----
__global__ __launch_bounds__(DPT) void k_degplace(const int* __restrict__ tmp1,
                                                  const int* __restrict__ coarseStart,
                                                  float* __restrict__ dis,
                                                  int* __restrict__ rowStart,
                                                  int* __restrict__ esrc, int N) {
    __shared__ int hist[256];
    __shared__ int scn[256];
    __shared__ int cur[256];
    int tid = threadIdx.x;
    int cb = blockIdx.x;
    int node0 = cb << 8;
    const int r0 = coarseStart[cb], r1 = coarseStart[cb + 1];
    if (tid < 256) hist[tid] = 0;
    __syncthreads();
    for (int i = r0 + tid; i < r1; i += DPT)
        atomicAdd(&hist[((unsigned)tmp1[i]) >> 17], 1);
    __syncthreads();
    int v = 0;
    if (tid < 256) { v = hist[tid]; scn[tid] = v; }
    __syncthreads();
    for (int off = 1; off < 256; off <<= 1) {
        int a = 0;
        if (tid < 256 && tid >= off) a = scn[tid - off];
        __syncthreads();
        if (tid < 256) scn[tid] += a;
        __syncthreads();
    }
    if (tid < 256) {
        int myStart = r0 + scn[tid] - v;
        cur[tid] = myStart;
        int node = node0 + tid;
        if (node < N) {
            dis[node] = rsqrtf((float)v + 1.0f);
            rowStart[node] = myStart;
        }
    }
    __syncthreads();
    for (int i = r0 + tid; i < r1; i += DPT) {
        int pk = tmp1[i];
        int dl = ((unsigned)pk) >> 17;
        int pos = atomicAdd(&cur[dl], 1);
        esrc[pos] = (pk & 0x1FFFF) << 7;     // byte offset of bf16 row
    }
}

// ------- MFMA transform: Hbs[N,64] = bf16( (X[N,K] @ W[K,64]) * dis[row] ) -------
// B-fragments read directly from pre-converted bf16 Wb [n][k] (L2-resident),
// no per-block LDS staging, no barrier.
template <int K, typename T>
__global__ __launch_bounds__(256) void k_mmx(const T* __restrict__ X,
                                             const unsigned short* __restrict__ Wb,
                                             const float* __restrict__ dis,
                                             unsigned short* __restrict__ Hbs, int N) {
    const int tid = threadIdx.x;
    const int lane = tid & 63;
    const int m16 = lane & 15;
    const int quad = lane >> 4;
    const int rowBase = blockIdx.x * 64 + (tid >> 6) * 16;
    const int rowc = min(rowBase + m16, N - 1);

    f32x4 acc0 = {0.f, 0.f, 0.f, 0.f};
    f32x4 acc1 = acc0, acc2 = acc0, acc3 = acc0;
    const T* xrow = X + (size_t)rowc * K;
#pragma unroll
    for (int k0 = 0; k0 < K; k0 += 32) {
        bf16x8 af;
        if constexpr (sizeof(T) == 4) {
            const float* xp = (const float*)xrow + k0 + quad * 8;
            float4 xa = *(const float4*)xp;
            float4 xb = *(const float4*)(xp + 4);
            af[0] = (short)f2bf(xa.x); af[1] = (short)f2bf(xa.y);
            af[2] = (short)f2bf(xa.z); af[3] = (short)f2bf(xa.w);
            af[4] = (short)f2bf(xb.x); af[5] = (short)f2bf(xb.y);
            af[6] = (short)f2bf(xb.z); af[7] = (short)f2bf(xb.w);
        } else {
            af = *(const bf16x8*)((const unsigned short*)xrow + k0 + quad * 8);
        }
        const unsigned short* wp = Wb + m16 * K + k0 + quad * 8;
        bf16x8 b0 = *(const bf16x8*)(wp);
        bf16x8 b1 = *(const bf16x8*)(wp + 16 * K);
        bf16x8 b2 = *(const bf16x8*)(wp + 32 * K);
        bf16x8 b3 = *(const bf16x8*)(wp + 48 * K);
        acc0 = __builtin_amdgcn_mfma_f32_16x16x32_bf16(af, b0, acc0, 0, 0, 0);
        acc1 = __builtin_amdgcn_mfma_f32_16x16x32_bf16(af, b1, acc1, 0, 0, 0);
        acc2 = __builtin_amdgcn_mfma_f32_16x16x32_bf16(af, b2, acc2, 0, 0, 0);
        acc3 = __builtin_amdgcn_mfma_f32_16x16x32_bf16(af, b3, acc3, 0, 0, 0);
    }
#pragma unroll
    for (int reg = 0; reg < 4; ++reg) {
        int r = rowBase + quad * 4 + reg;
        if (r < N) {
            float dsc = dis[r];
            unsigned short* hp = Hbs + (size_t)r * 64 + m16;
            hp[0]  = f2bf(acc0[reg] * dsc);
            hp[16] = f2bf(acc1[reg] * dsc);
            hp[32] = f2bf(acc2[reg] * dsc);
            hp[48] = f2bf(acc3[reg] * dsc);
        }
    }
}

#define BLO(d) __uint_as_float((d) << 16)
#define BHI(d) __uint_as_float((d) & 0xFFFF0000u)
#define ACC4(L, H, Q) { L.x += BLO((Q).x); L.y += BHI((Q).x);                  \
                        L.z += BLO((Q).y); L.w += BHI((Q).y);                  \
                        H.x += BLO((Q).z); H.y += BHI((Q).z);                  \
                        H.z += BLO((Q).w); H.w += BHI((Q).w); }

// octet-scheme gather body (round-7 proven): computes aL/aH for node n of this
// octet; all shfl sources stay inside the octet and bounds are octet-uniform.
#define GATHER_OCTET_BODY()                                                    \
    unsigned eoff = (Rq + c < Rq1) ? (unsigned)esrc[Rq + c] : 0u;              \
    for (int bb = Rq; bb < Rq1; bb += 8) {                                     \
        int cnt = min(8, Rq1 - bb);                                            \
        unsigned eoffN = (bb + 8 + c < Rq1) ? (unsigned)esrc[bb + 8 + c] : 0u; \
        if (cnt == 8) {                                                        \
            unsigned o0 = __shfl(eoff, ob + 0, 64);                            \
            unsigned o1 = __shfl(eoff, ob + 1, 64);                            \
            unsigned o2 = __shfl(eoff, ob + 2, 64);                            \
            unsigned o3 = __shfl(eoff, ob + 3, 64);                            \
            unsigned o4 = __shfl(eoff, ob + 4, 64);                            \
            unsigned o5 = __shfl(eoff, ob + 5, 64);                            \
            unsigned o6 = __shfl(eoff, ob + 6, 64);                            \
            unsigned o7 = __shfl(eoff, ob + 7, 64);                            \
            uint4 q0 = *(const uint4*)(hb + o0);                               \
            uint4 q1 = *(const uint4*)(hb + o1);                               \
            uint4 q2 = *(const uint4*)(hb + o2);                               \
            uint4 q3 = *(const uint4*)(hb + o3);                               \
            uint4 q4 = *(const uint4*)(hb + o4);                               \
            uint4 q5 = *(const uint4*)(hb + o5);                               \
            uint4 q6 = *(const uint4*)(hb + o6);                               \
            uint4 q7 = *(const uint4*)(hb + o7);                               \
            ACC4(aL, aH, q0) ACC4(aL, aH, q1) ACC4(aL, aH, q2) ACC4(aL, aH, q3)\
            ACC4(aL, aH, q4) ACC4(aL, aH, q5) ACC4(aL, aH, q6) ACC4(aL, aH, q7)\
        } else {                                                               \
            int j = 0;                                                         \
            if (j + 4 <= cnt) {                                                \
                unsigned o0 = __shfl(eoff, ob + j + 0, 64);                    \
                unsigned o1 = __shfl(eoff, ob + j + 1, 64);                    \
                unsigned o2 = __shfl(eoff, ob + j + 2, 64);                    \
                unsigned o3 = __shfl(eoff, ob + j + 3, 64);                    \
                uint4 q0 = *(const uint4*)(hb + o0);                           \
                uint4 q1 = *(const uint4*)(hb + o1);                           \
                uint4 q2 = *(const uint4*)(hb + o2);                           \
                uint4 q3 = *(const uint4*)(hb + o3);                           \
                ACC4(aL, aH, q0) ACC4(aL, aH, q1)                              \
                ACC4(aL, aH, q2) ACC4(aL, aH, q3)                              \
                j += 4;                                                        \
            }                                                                  \
            if (j < cnt) {                                                     \
                bool v1 = j + 1 < cnt, v2 = j + 2 < cnt;                       \
                unsigned o0 = __shfl(eoff, ob + j, 64);                        \
                unsigned o1 = __shfl(eoff, v1 ? ob + j + 1 : ob + j, 64);      \
                unsigned o2 = __shfl(eoff, v2 ? ob + j + 2 : ob + j, 64);      \
                uint4 q0 = *(const uint4*)(hb + o0);                           \
                uint4 q1 = *(const uint4*)(hb + o1);                           \
                uint4 q2 = *(const uint4*)(hb + o2);                           \
                if (!v1) { q1.x = q1.y = q1.z = q1.w = 0u; }                   \
                if (!v2) { q2.x = q2.y = q2.z = q2.w = 0u; }                   \
                ACC4(aL, aH, q0) ACC4(aL, aH, q1) ACC4(aL, aH, q2)             \
            }                                                                  \
        }                                                                      \
        eoff = eoffN;                                                          \
    }

// ------- FUSED layer-1 gather + layer-2 transform (256 threads) --------------
// 4 waves gather 8 nodes each (octet scheme) into LDS; waves 0-1 run the K=64
// MFMA transform. W2 fragments read directly from bf16 Wb2 global (L2-resident)
// -- no per-block weight staging, LDS = Hrow only (4.6 KB).
__global__ __launch_bounds__(256) void k_gmx(const unsigned short* __restrict__ Hbs,
                                             const int* __restrict__ esrc,
                                             const int* __restrict__ rowStart,
                                             const float* __restrict__ dis,
                                             const float* __restrict__ b,   // b1
                                             const unsigned short* __restrict__ Wb2,
                                             unsigned short* __restrict__ Hout,
                                             int N) {
    __shared__ unsigned short Hrow[32 * 72];   // 32 gathered rows, +8 pad
    const int tid = threadIdx.x;
    const int lane = tid & 63;
    const int c = lane & 7;            // 16B chunk of the 128B row
    const int oct = lane >> 3;         // octet index == node slot
    const int ob = oct << 3;           // octet's first lane (shfl base)
    const int wv = tid >> 6;           // wave 0..3
    const int g0 = blockIdx.x * 32 + wv * 8;
    const char* hb = (const char*)Hbs + c * 16;

    int rb = rowStart[min(g0 + lane, N)];
    int Rq  = __shfl(rb, oct, 64);
    int Rq1 = __shfl(rb, oct + 1, 64);
    int n = g0 + oct;
    int nc = min(n, N - 1);            // n>=N octets: Rq==Rq1==E (no edges)

    float4 aL, aH;
    {
        uint4 sd = *(const uint4*)(hb + ((size_t)nc << 7));   // self-loop seed
        aL.x = BLO(sd.x); aL.y = BHI(sd.x); aL.z = BLO(sd.y); aL.w = BHI(sd.y);
        aH.x = BLO(sd.z); aH.y = BHI(sd.z); aH.z = BLO(sd.w); aH.w = BHI(sd.w);
    }
    GATHER_OCTET_BODY()

    {   // epilogue: relu row -> LDS (rows for n>=N are garbage, outputs guarded)
        float ds = dis[nc];
        float4 bL = ((const float4*)b)[2 * c];
        float4 bH = ((const float4*)b)[2 * c + 1];
        uint4 pv;
        pv.x = (unsigned)f2bf(fmaxf(aL.x * ds + bL.x, 0.f))
             | ((unsigned)f2bf(fmaxf(aL.y * ds + bL.y, 0.f)) << 16);
        pv.y = (unsigned)f2bf(fmaxf(aL.z * ds + bL.z, 0.f))
             | ((unsigned)f2bf(fmaxf(aL.w * ds + bL.w, 0.f)) << 16);
        pv.z = (unsigned)f2bf(fmaxf(aH.x * ds + bH.x, 0.f))
             | ((unsigned)f2bf(fmaxf(aH.y * ds + bH.y, 0.f)) << 16);
        pv.w = (unsigned)f2bf(fmaxf(aH.z * ds + bH.z, 0.f))
             | ((unsigned)f2bf(fmaxf(aH.w * ds + bH.w, 0.f)) << 16);
        ((uint4*)&Hrow[(wv * 8 + oct) * 72])[c] = pv;   // 144B row stride, 16B aligned
    }
    __syncthreads();

    // ---- layer-2 transform: waves 0-1, 16 rows each, K=64 from LDS ----
    if (wv < 2) {
        const int m16 = lane & 15;
        const int quad = lane >> 4;
        const int rowBase = blockIdx.x * 32 + wv * 16;
        f32x4 acc0 = {0.f, 0.f, 0.f, 0.f};
        f32x4 acc1 = acc0, acc2 = acc0, acc3 = acc0;
#pragma unroll
        for (int k0 = 0; k0 < 64; k0 += 32) {
            bf16x8 af = *(const bf16x8*)&Hrow[(wv * 16 + m16) * 72 + k0 + quad * 8];
            const unsigned short* wp = Wb2 + m16 * 64 + k0 + quad * 8;
            bf16x8 b0 = *(const bf16x8*)(wp);
            bf16x8 b1 = *(const bf16x8*)(wp + 16 * 64);
            bf16x8 b2 = *(const bf16x8*)(wp + 32 * 64);
            bf16x8 b3 = *(const bf16x8*)(wp + 48 * 64);
            acc0 = __builtin_amdgcn_mfma_f32_16x16x32_bf16(af, b0, acc0, 0, 0, 0);
            acc1 = __builtin_amdgcn_mfma_f32_16x16x32_bf16(af, b1, acc1, 0, 0, 0);
            acc2 = __builtin_amdgcn_mfma_f32_16x16x32_bf16(af, b2, acc2, 0, 0, 0);
            acc3 = __builtin_amdgcn_mfma_f32_16x16x32_bf16(af, b3, acc3, 0, 0, 0);
        }
#pragma unroll
        for (int reg = 0; reg < 4; ++reg) {
            int r = rowBase + quad * 4 + reg;
            if (r < N) {
                float dsc = dis[r];
                unsigned short* hp = Hout + (size_t)r * 64 + m16;
                hp[0]  = f2bf(acc0[reg] * dsc);
                hp[16] = f2bf(acc1[reg] * dsc);
                hp[32] = f2bf(acc2[reg] * dsc);
                hp[48] = f2bf(acc3[reg] * dsc);
            }
        }
    }
}

// ------- layer-2 gather fused with W3 dot (round-7 proven octet scheme) ------
__global__ __launch_bounds__(256) void k_gatherW3(const unsigned short* __restrict__ Hbs,
                                                  const int* __restrict__ esrc,
                                                  const int* __restrict__ rowStart,
                                                  const float* __restrict__ dis,
                                                  const float* __restrict__ b,
                                                  const float* __restrict__ W3,
                                                  const float* __restrict__ b3,
                                                  float* __restrict__ colS,
                                                  float* __restrict__ outF,
                                                  int N) {
    int lane = threadIdx.x & 63;
    int c = lane & 7;
    int oct = lane >> 3;
    int ob = oct << 3;
    int wave = (blockIdx.x * 256 + threadIdx.x) >> 6;
    int g0 = wave * 8;
    if (g0 >= N) return;
    const char* hb = (const char*)Hbs + c * 16;

    int rb = rowStart[min(g0 + lane, N)];
    int Rq  = __shfl(rb, oct, 64);
    int Rq1 = __shfl(rb, oct + 1, 64);
    int n = g0 + oct;
    int nc = min(n, N - 1);

    float4 aL, aH;
    {
        uint4 sd = *(const uint4*)(hb + ((size_t)nc << 7));
        aL.x = BLO(sd.x); aL.y = BHI(sd.x); aL.z = BLO(sd.y); aL.w = BHI(sd.y);
        aH.x = BLO(sd.z); aH.y = BHI(sd.z); aH.z = BLO(sd.w); aH.w = BHI(sd.w);
    }
    GATHER_OCTET_BODY()

    float ds = dis[nc];
    float4 bL = ((const float4*)b)[2 * c];
    float4 bH = ((const float4*)b)[2 * c + 1];
    float4 vL, vH;
    vL.x = fmaxf(aL.x * ds + bL.x, 0.f);
    vL.y = fmaxf(aL.y * ds + bL.y, 0.f);
    vL.z = fmaxf(aL.z * ds + bL.z, 0.f);
    vL.w = fmaxf(aL.w * ds + bL.w, 0.f);
    vH.x = fmaxf(aH.x * ds + bH.x, 0.f);
    vH.y = fmaxf(aH.y * ds + bH.y, 0.f);
    vH.z = fmaxf(aH.z * ds + bH.z, 0.f);
    vH.w = fmaxf(aH.w * ds + bH.w, 0.f);

    float4 wL = ((const float4*)W3)[2 * c];
    float4 wH = ((const float4*)W3)[2 * c + 1];
    float t = vL.x * wL.x + vL.y * wL.y + vL.z * wL.z + vL.w * wL.w
            + vH.x * wH.x + vH.y * wH.y + vH.z * wH.z + vH.w * wH.w;
    t += __shfl_xor(t, 1, 64);
    t += __shfl_xor(t, 2, 64);
    t += __shfl_xor(t, 4, 64);
    if (c == 0 && n < N) {
        colS[n] = t * ds;
        outF[n] = t * ds * ds + b3[0];
    }
}

// layer-3 aggregation: stage block's colS values in LDS, per-node sum from LDS
__global__ __launch_bounds__(256) void k_gather1(const float* __restrict__ colS,
                                                 const int* __restrict__ esrc,
                                                 const int* __restrict__ rowStart,
                                                 const float* __restrict__ dis,
                                                 float* __restrict__ out, int N) {
    __shared__ float ls[G1CAP];
    int tid = threadIdx.x;
    int n0 = blockIdx.x * 256;
    int nEnd = min(n0 + 256, N);
    int r0 = rowStart[n0];
    int r1 = rowStart[nEnd];
    int cnt = r1 - r0;
    if (cnt <= G1CAP) {
        for (int i = tid; i < cnt; i += 256)
            ls[i] = colS[((unsigned)esrc[r0 + i]) >> 7];
        __syncthreads();
        int n = n0 + tid;
        if (n < N) {
            int a = rowStart[n] - r0, bnd = rowStart[n + 1] - r0;
            float acc = 0.0f;
            for (int e = a; e < bnd; ++e) acc += ls[e];
            out[n] += acc * dis[n];
        }
    } else {   // statistically unreachable fallback
        int n = n0 + tid;
        if (n < N) {
            int a = rowStart[n], bnd = rowStart[n + 1];
            float acc = 0.0f;
            for (int e = a; e < bnd; ++e) acc += colS[((unsigned)esrc[e]) >> 7];
            out[n] += acc * dis[n];
        }
    }
}

extern "C" void kernel_launch(void* const* d_in, const int* in_sizes, int n_in,
                              void* d_out, int out_size, void* d_ws, size_t ws_size,
                              hipStream_t stream) {
    const float* x  = (const float*)d_in[0];
    const int*   ei = (const int*)d_in[1];
    const float* W1 = (const float*)d_in[2];
    const float* b1 = (const float*)d_in[3];
    const float* W2 = (const float*)d_in[4];
    const float* b2 = (const float*)d_in[5];
    const float* W3 = (const float*)d_in[6];
    const float* b3 = (const float*)d_in[7];
    float* out = (float*)d_out;

    const int N = in_sizes[0] / IN_DIM;     // 100000
    const int E = in_sizes[1] / 2;          // 1600000
    const int* src = ei;
    const int* dst = ei + E;
    const int NC = (N + 255) >> 8;          // 391 coarse buckets
    const int NBLK = (E + EPB - 1) / EPB;   // 391 partition blocks

    // ---- workspace layout ----
    char* w = (char*)d_ws;
    auto alloc = [&](size_t bytes) {
        char* p = w;
        w += (bytes + 1023) & ~(size_t)1023;
        return p;
    };
    float*          dis        = (float*)alloc((size_t)N * 4);
    unsigned short* Hbs        = (unsigned short*)alloc((size_t)N * 64 * 2);
    unsigned short* Hb1        = (unsigned short*)alloc((size_t)N * 64 * 2);
    float*          colS       = (float*)alloc((size_t)N * 4);
    int*            rowStart   = (int*)alloc((size_t)(N + 1) * 4);
    int*            bktTotal   = (int*)alloc((size_t)MAXC * 4);
    int*            coarseStart= (int*)alloc((size_t)(MAXC + 1) * 4);
    int*            hmat       = (int*)alloc((size_t)MAXB * MAXC * 4);
    int*            esrc       = (int*)alloc((size_t)E * 4 + 1024);
    int*            tmp1       = (int*)alloc((size_t)E * 4);
    int*            ctr        = (int*)alloc(64);
    unsigned short* Wb1        = (unsigned short*)alloc((size_t)IN_DIM * HID * 2);
    unsigned short* Wb2        = (unsigned short*)alloc((size_t)HID * HID * 2);

    const int NB_N   = (N + 255) / 256;
    const int NB_MX  = (N + 63) / 64;                    // MFMA transform blocks
    const int NB_G8  = (((N + 7) / 8) * 64 + 255) / 256; // 8 nodes per wave
    const int NB_GMX = (N + 31) / 32;                    // 32 nodes per block

    // ---- deterministic partition (4 kernels; cscan folded into bktscan) ----
    k_hist2<<<NBLK, 256, 0, stream>>>(dst, hmat, ctr, W1, W2, Wb1, Wb2, E, NC);
    k_bktscan<<<NC, 512, 0, stream>>>(hmat, bktTotal, ctr, coarseStart, rowStart,
                                      NBLK, NC, N, E);
    k_part1<<<NBLK, 256, 0, stream>>>(src, dst, hmat, coarseStart, tmp1, E, NC);
    k_degplace<<<NC, DPT, 0, stream>>>(tmp1, coarseStart, dis, rowStart, esrc, N);

    // ---- layer 1 transform ----
    k_mmx<IN_DIM, float><<<NB_MX, 256, 0, stream>>>(x, Wb1, dis, Hbs, N);

    // ---- fused: layer-1 gather + layer-2 transform (Hbs -> Hb1, via LDS) ----
    k_gmx<<<NB_GMX, 256, 0, stream>>>(Hbs, esrc, rowStart, dis, b1, Wb2, Hb1, N);

    // ---- layer-2 gather fused with W3 dot ----
    k_gatherW3<<<NB_G8, 256, 0, stream>>>(Hb1, esrc, rowStart, dis, b2,
                                          W3, b3, colS, out, N);

    // ---- layer 3 aggregation ----
    k_gather1<<<NB_N, 256, 0, stream>>>(colS, esrc, rowStart, dis, out, N);
}

// Round 12
// 227.943 us; speedup vs baseline: 1.0591x; 1.0591x over previous
//
#include <hip/hip_runtime.h>

#define IN_DIM 128
#define HID 64
#define MAXC 400            // >= ceil(N/256); N=100000 -> 391 coarse buckets
#define MAXB 512            // >= NBLK = ceil(E/EPB) = 391
#define EPB 4096
#define DPT 512             // degplace threads per block
#define G1CAP 6144          // LDS floats for k_gather1 staging (E[block]=4096, +32 sigma)

// ---- bf16 helpers (RNE) ----
static __device__ __forceinline__ unsigned short f2bf(float f) {
    unsigned u = __float_as_uint(f);
    u += 0x7FFF + ((u >> 16) & 1);
    return (unsigned short)(u >> 16);
}

typedef short bf16x8 __attribute__((ext_vector_type(8)));
typedef float f32x4 __attribute__((ext_vector_type(4)));

// ---- pass 0: per-block bucket histogram -> hmat[blk][cb]; blk0 zeroes ctr ----
__global__ __launch_bounds__(256) void k_hist2(const int* __restrict__ dst,
                                               int* __restrict__ hmat,
                                               int* __restrict__ ctr, int E, int NC) {
    __shared__ int h[MAXC];
    int tid = threadIdx.x, blk = blockIdx.x;
    if (blk == 0 && tid == 0) ctr[0] = 0;
    for (int i = tid; i < NC; i += 256) h[i] = 0;
    __syncthreads();
    int e0 = blk * EPB, e1 = min(e0 + EPB, E);
    for (int e = e0 + tid; e < e1; e += 256) atomicAdd(&h[dst[e] >> 8], 1);
    __syncthreads();
    for (int i = tid; i < NC; i += 256) hmat[blk * MAXC + i] = h[i];
}

// ---- per-bucket exclusive scan across blocks + (last block) bucket-total scan ----
// Cross-block comms via device-scope atomics only (coherence point), per G16.
__global__ __launch_bounds__(512) void k_bktscan(int* __restrict__ hmat,
                                                 int* __restrict__ bktTotal,
                                                 int* __restrict__ ctr,
                                                 int* __restrict__ coarseStart,
                                                 int* __restrict__ rowStart,
                                                 int NBLK, int NC, int N, int E) {
    __shared__ int tmp[512];
    __shared__ int lastFlag;
    int cb = blockIdx.x;
    int t = threadIdx.x;
    int v = (t < NBLK) ? hmat[t * MAXC + cb] : 0;
    tmp[t] = v;
    __syncthreads();
    for (int off = 1; off < 512; off <<= 1) {
        int a = (t >= off) ? tmp[t - off] : 0;
        __syncthreads();
        tmp[t] += a;
        __syncthreads();
    }
    if (t < NBLK) hmat[t * MAXC + cb] = tmp[t] - v;   // exclusive prefix within bucket
    if (t == 511) atomicExch(&bktTotal[cb], tmp[511]); // coherence-point publish
    __syncthreads();                                   // drains the atomic (vmcnt)
    if (t == 0) lastFlag = (atomicAdd(ctr, 1) == (int)gridDim.x - 1);
    __syncthreads();
    if (!lastFlag) return;
    // last arriving block: scan bucket totals -> coarseStart
    int v2 = (t < NC) ? atomicAdd(&bktTotal[t], 0) : 0;  // coherence-point read
    tmp[t] = v2;
    __syncthreads();
    for (int off = 1; off < 512; off <<= 1) {
        int a = (t >= off) ? tmp[t - off] : 0;
        __syncthreads();
        tmp[t] += a;
        __syncthreads();
    }
    int excl = tmp[t] - v2;
    if (t < NC) coarseStart[t] = excl;
    if (t == NC - 1) coarseStart[NC] = excl + v2;   // == E
    if (t == 0) rowStart[N] = E;
}

// ---- pass 1: deterministic placement into dense coarse-sorted array ----
__global__ __launch_bounds__(256) void k_part1(const int* __restrict__ src,
                                               const int* __restrict__ dst,
                                               const int* __restrict__ hmat,
                                               const int* __restrict__ coarseStart,
                                               int* __restrict__ tmp1,
                                               int E, int NC) {
    __shared__ int bcnt[MAXC];
    __shared__ int bbase[MAXC];
    int tid = threadIdx.x, blk = blockIdx.x;
    for (int i = tid; i < NC; i += 256) {
        bcnt[i] = 0;
        bbase[i] = coarseStart[i] + hmat[blk * MAXC + i];   // coalesced
    }
    __syncthreads();
    int e0 = blk * EPB, e1 = min(e0 + EPB, E);
    for (int e = e0 + tid; e < e1; e += 256) {
        int s = src[e], d = dst[e];
        int cb = d >> 8;
        int slot = bbase[cb] + atomicAdd(&bcnt[cb], 1);
        tmp1[slot] = s | ((d & 255) << 17);
    }
}

// ---- pass 2 (fused): per-bucket degree->dis/rowStart, then place into CSR ----
__global__ __launch_bounds__(DPT) void k_degplace(const int* __restrict__ tmp1,
                                                  const int* __restrict__ coarseStart,
                                                  float* __restrict__ dis,
                                                  int* __restrict__ rowStart,
                                                  int* __restrict__ esrc, int N) {
    __shared__ int hist[256];
    __shared__ int scn[256];
    __shared__ int cur[256];
    int tid = threadIdx.x;
    int cb = blockIdx.x;
    int node0 = cb << 8;
    const int r0 = coarseStart[cb], r1 = coarseStart[cb + 1];
    if (tid < 256) hist[tid] = 0;
    __syncthreads();
    for (int i = r0 + tid; i < r1; i += DPT)
        atomicAdd(&hist[((unsigned)tmp1[i]) >> 17], 1);
    __syncthreads();
    int v = 0;
    if (tid < 256) { v = hist[tid]; scn[tid] = v; }
    __syncthreads();
    for (int off = 1; off < 256; off <<= 1) {
        int a = 0;
        if (tid < 256 && tid >= off) a = scn[tid - off];
        __syncthreads();
        if (tid < 256) scn[tid] += a;
        __syncthreads();
    }
    if (tid < 256) {
        int myStart = r0 + scn[tid] - v;
        cur[tid] = myStart;
        int node = node0 + tid;
        if (node < N) {
            dis[node] = rsqrtf((float)v + 1.0f);
            rowStart[node] = myStart;
        }
    }
    __syncthreads();
    for (int i = r0 + tid; i < r1; i += DPT) {
        int pk = tmp1[i];
        int dl = ((unsigned)pk) >> 17;
        int pos = atomicAdd(&cur[dl], 1);
        esrc[pos] = (pk & 0x1FFFF) << 7;     // byte offset of bf16 row
    }
}

// ------- MFMA transform: Hbs[N,64] = bf16( (X[N,K] @ W[K,64]) * dis[row] ) -------
template <int K, typename T>
__global__ __launch_bounds__(256) void k_mmx(const T* __restrict__ X,
                                             const float* __restrict__ W,
                                             const float* __restrict__ dis,
                                             unsigned short* __restrict__ Hbs, int N) {
    constexpr int WP = K + 8;
    __shared__ unsigned short Wt[64 * WP];
    const int tid = threadIdx.x;
    for (int i = tid; i < K * 64; i += 256) {
        int k = i >> 6, n = i & 63;
        Wt[n * WP + k] = f2bf(W[i]);
    }
    __syncthreads();
    const int lane = tid & 63;
    const int m16 = lane & 15;
    const int quad = lane >> 4;
    const int rowBase = blockIdx.x * 64 + (tid >> 6) * 16;
    const int rowc = min(rowBase + m16, N - 1);

    f32x4 acc0 = {0.f, 0.f, 0.f, 0.f};
    f32x4 acc1 = acc0, acc2 = acc0, acc3 = acc0;
    const T* xrow = X + (size_t)rowc * K;
#pragma unroll
    for (int k0 = 0; k0 < K; k0 += 32) {
        bf16x8 af;
        if constexpr (sizeof(T) == 4) {
            const float* xp = (const float*)xrow + k0 + quad * 8;
            float4 xa = *(const float4*)xp;
            float4 xb = *(const float4*)(xp + 4);
            af[0] = (short)f2bf(xa.x); af[1] = (short)f2bf(xa.y);
            af[2] = (short)f2bf(xa.z); af[3] = (short)f2bf(xa.w);
            af[4] = (short)f2bf(xb.x); af[5] = (short)f2bf(xb.y);
            af[6] = (short)f2bf(xb.z); af[7] = (short)f2bf(xb.w);
        } else {
            af = *(const bf16x8*)((const unsigned short*)xrow + k0 + quad * 8);
        }
        const unsigned short* wp = &Wt[m16 * WP + k0 + quad * 8];
        bf16x8 b0 = *(const bf16x8*)(wp);
        bf16x8 b1 = *(const bf16x8*)(wp + 16 * WP);
        bf16x8 b2 = *(const bf16x8*)(wp + 32 * WP);
        bf16x8 b3 = *(const bf16x8*)(wp + 48 * WP);
        acc0 = __builtin_amdgcn_mfma_f32_16x16x32_bf16(af, b0, acc0, 0, 0, 0);
        acc1 = __builtin_amdgcn_mfma_f32_16x16x32_bf16(af, b1, acc1, 0, 0, 0);
        acc2 = __builtin_amdgcn_mfma_f32_16x16x32_bf16(af, b2, acc2, 0, 0, 0);
        acc3 = __builtin_amdgcn_mfma_f32_16x16x32_bf16(af, b3, acc3, 0, 0, 0);
    }
#pragma unroll
    for (int reg = 0; reg < 4; ++reg) {
        int r = rowBase + quad * 4 + reg;
        if (r < N) {
            float dsc = dis[r];
            unsigned short* hp = Hbs + (size_t)r * 64 + m16;
            hp[0]  = f2bf(acc0[reg] * dsc);
            hp[16] = f2bf(acc1[reg] * dsc);
            hp[32] = f2bf(acc2[reg] * dsc);
            hp[48] = f2bf(acc3[reg] * dsc);
        }
    }
}

#define BLO(d) __uint_as_float((d) << 16)
#define BHI(d) __uint_as_float((d) & 0xFFFF0000u)
#define ACC4(L, H, Q) { L.x += BLO((Q).x); L.y += BHI((Q).x);                  \
                        L.z += BLO((Q).y); L.w += BHI((Q).y);                  \
                        H.x += BLO((Q).z); H.y += BHI((Q).z);                  \
                        H.z += BLO((Q).w); H.w += BHI((Q).w); }

// octet-scheme gather body (round-7 proven): computes aL/aH for node n of this
// octet; all shfl sources stay inside the octet and bounds are octet-uniform.
#define GATHER_OCTET_BODY()                                                    \
    unsigned eoff = (Rq + c < Rq1) ? (unsigned)esrc[Rq + c] : 0u;              \
    for (int bb = Rq; bb < Rq1; bb += 8) {                                     \
        int cnt = min(8, Rq1 - bb);                                            \
        unsigned eoffN = (bb + 8 + c < Rq1) ? (unsigned)esrc[bb + 8 + c] : 0u; \
        if (cnt == 8) {                                                        \
            unsigned o0 = __shfl(eoff, ob + 0, 64);                            \
            unsigned o1 = __shfl(eoff, ob + 1, 64);                            \
            unsigned o2 = __shfl(eoff, ob + 2, 64);                            \
            unsigned o3 = __shfl(eoff, ob + 3, 64);                            \
            unsigned o4 = __shfl(eoff, ob + 4, 64);                            \
            unsigned o5 = __shfl(eoff, ob + 5, 64);                            \
            unsigned o6 = __shfl(eoff, ob + 6, 64);                            \
            unsigned o7 = __shfl(eoff, ob + 7, 64);                            \
            uint4 q0 = *(const uint4*)(hb + o0);                               \
            uint4 q1 = *(const uint4*)(hb + o1);                               \
            uint4 q2 = *(const uint4*)(hb + o2);                               \
            uint4 q3 = *(const uint4*)(hb + o3);                               \
            uint4 q4 = *(const uint4*)(hb + o4);                               \
            uint4 q5 = *(const uint4*)(hb + o5);                               \
            uint4 q6 = *(const uint4*)(hb + o6);                               \
            uint4 q7 = *(const uint4*)(hb + o7);                               \
            ACC4(aL, aH, q0) ACC4(aL, aH, q1) ACC4(aL, aH, q2) ACC4(aL, aH, q3)\
            ACC4(aL, aH, q4) ACC4(aL, aH, q5) ACC4(aL, aH, q6) ACC4(aL, aH, q7)\
        } else {                                                               \
            int j = 0;                                                         \
            if (j + 4 <= cnt) {                                                \
                unsigned o0 = __shfl(eoff, ob + j + 0, 64);                    \
                unsigned o1 = __shfl(eoff, ob + j + 1, 64);                    \
                unsigned o2 = __shfl(eoff, ob + j + 2, 64);                    \
                unsigned o3 = __shfl(eoff, ob + j + 3, 64);                    \
                uint4 q0 = *(const uint4*)(hb + o0);                           \
                uint4 q1 = *(const uint4*)(hb + o1);                           \
                uint4 q2 = *(const uint4*)(hb + o2);                           \
                uint4 q3 = *(const uint4*)(hb + o3);                           \
                ACC4(aL, aH, q0) ACC4(aL, aH, q1)                              \
                ACC4(aL, aH, q2) ACC4(aL, aH, q3)                              \
                j += 4;                                                        \
            }                                                                  \
            if (j < cnt) {                                                     \
                bool v1 = j + 1 < cnt, v2 = j + 2 < cnt;                       \
                unsigned o0 = __shfl(eoff, ob + j, 64);                        \
                unsigned o1 = __shfl(eoff, v1 ? ob + j + 1 : ob + j, 64);      \
                unsigned o2 = __shfl(eoff, v2 ? ob + j + 2 : ob + j, 64);      \
                uint4 q0 = *(const uint4*)(hb + o0);                           \
                uint4 q1 = *(const uint4*)(hb + o1);                           \
                uint4 q2 = *(const uint4*)(hb + o2);                           \
                if (!v1) { q1.x = q1.y = q1.z = q1.w = 0u; }                   \
                if (!v2) { q2.x = q2.y = q2.z = q2.w = 0u; }                   \
                ACC4(aL, aH, q0) ACC4(aL, aH, q1) ACC4(aL, aH, q2)             \
            }                                                                  \
        }                                                                      \
        eoff = eoffN;                                                          \
    }

// ------- FUSED layer-1 gather + layer-2 transform (256-thread rebalance) -----
// 256 threads = 4 waves; wave wv gathers 8 nodes (octet scheme) into LDS; then
// waves 0-1 run the K=64 MFMA transform over the 32 rows. Smaller barrier set
// (max over 4 waves, not 8) cuts straggler time; 8 blocks/CU schedulable.
__global__ __launch_bounds__(256) void k_gmx(const unsigned short* __restrict__ Hbs,
                                             const int* __restrict__ esrc,
                                             const int* __restrict__ rowStart,
                                             const float* __restrict__ dis,
                                             const float* __restrict__ b,   // b1
                                             const float* __restrict__ W,   // W2
                                             unsigned short* __restrict__ Hout,
                                             int N) {
    __shared__ unsigned short Hrow[32 * 72];   // 32 gathered rows, +8 pad
    __shared__ unsigned short Wt[64 * 72];     // W2^T staged [n][k], +8 pad
    const int tid = threadIdx.x;
    for (int i = tid; i < 64 * 64; i += 256) { // stage W2 (f32 [k][n]) as bf16
        int k = i >> 6, n = i & 63;
        Wt[n * 72 + k] = f2bf(W[i]);
    }
    const int lane = tid & 63;
    const int c = lane & 7;            // 16B chunk of the 128B row
    const int oct = lane >> 3;         // octet index == node slot
    const int ob = oct << 3;           // octet's first lane (shfl base)
    const int wv = tid >> 6;           // wave 0..3
    const int g0 = blockIdx.x * 32 + wv * 8;
    const char* hb = (const char*)Hbs + c * 16;

    int rb = rowStart[min(g0 + lane, N)];
    int Rq  = __shfl(rb, oct, 64);
    int Rq1 = __shfl(rb, oct + 1, 64);
    int n = g0 + oct;
    int nc = min(n, N - 1);            // n>=N octets: Rq==Rq1==E (no edges)

    float4 aL, aH;
    {
        uint4 sd = *(const uint4*)(hb + ((size_t)nc << 7));   // self-loop seed
        aL.x = BLO(sd.x); aL.y = BHI(sd.x); aL.z = BLO(sd.y); aL.w = BHI(sd.y);
        aH.x = BLO(sd.z); aH.y = BHI(sd.z); aH.z = BLO(sd.w); aH.w = BHI(sd.w);
    }
    GATHER_OCTET_BODY()

    {   // epilogue: relu row -> LDS (rows for n>=N are garbage, outputs guarded)
        float ds = dis[nc];
        float4 bL = ((const float4*)b)[2 * c];
        float4 bH = ((const float4*)b)[2 * c + 1];
        uint4 pv;
        pv.x = (unsigned)f2bf(fmaxf(aL.x * ds + bL.x, 0.f))
             | ((unsigned)f2bf(fmaxf(aL.y * ds + bL.y, 0.f)) << 16);
        pv.y = (unsigned)f2bf(fmaxf(aL.z * ds + bL.z, 0.f))
             | ((unsigned)f2bf(fmaxf(aL.w * ds + bL.w, 0.f)) << 16);
        pv.z = (unsigned)f2bf(fmaxf(aH.x * ds + bH.x, 0.f))
             | ((unsigned)f2bf(fmaxf(aH.y * ds + bH.y, 0.f)) << 16);
        pv.w = (unsigned)f2bf(fmaxf(aH.z * ds + bH.z, 0.f))
             | ((unsigned)f2bf(fmaxf(aH.w * ds + bH.w, 0.f)) << 16);
        ((uint4*)&Hrow[(wv * 8 + oct) * 72])[c] = pv;   // 144B row stride, 16B aligned
    }
    __syncthreads();

    // ---- layer-2 transform: waves 0-1, 16 rows each, K=64 from LDS ----
    if (wv < 2) {
        const int m16 = lane & 15;
        const int quad = lane >> 4;
        const int rowBase = blockIdx.x * 32 + wv * 16;
        f32x4 acc0 = {0.f, 0.f, 0.f, 0.f};
        f32x4 acc1 = acc0, acc2 = acc0, acc3 = acc0;
#pragma unroll
        for (int k0 = 0; k0 < 64; k0 += 32) {
            bf16x8 af = *(const bf16x8*)&Hrow[(wv * 16 + m16) * 72 + k0 + quad * 8];
            const unsigned short* wp = &Wt[m16 * 72 + k0 + quad * 8];
            bf16x8 b0 = *(const bf16x8*)(wp);
            bf16x8 b1 = *(const bf16x8*)(wp + 16 * 72);
            bf16x8 b2 = *(const bf16x8*)(wp + 32 * 72);
            bf16x8 b3 = *(const bf16x8*)(wp + 48 * 72);
            acc0 = __builtin_amdgcn_mfma_f32_16x16x32_bf16(af, b0, acc0, 0, 0, 0);
            acc1 = __builtin_amdgcn_mfma_f32_16x16x32_bf16(af, b1, acc1, 0, 0, 0);
            acc2 = __builtin_amdgcn_mfma_f32_16x16x32_bf16(af, b2, acc2, 0, 0, 0);
            acc3 = __builtin_amdgcn_mfma_f32_16x16x32_bf16(af, b3, acc3, 0, 0, 0);
        }
#pragma unroll
        for (int reg = 0; reg < 4; ++reg) {
            int r = rowBase + quad * 4 + reg;
            if (r < N) {
                float dsc = dis[r];
                unsigned short* hp = Hout + (size_t)r * 64 + m16;
                hp[0]  = f2bf(acc0[reg] * dsc);
                hp[16] = f2bf(acc1[reg] * dsc);
                hp[32] = f2bf(acc2[reg] * dsc);
                hp[48] = f2bf(acc3[reg] * dsc);
            }
        }
    }
}

// ------- layer-2 gather fused with W3 dot (round-7 proven octet scheme) ------
__global__ __launch_bounds__(256) void k_gatherW3(const unsigned short* __restrict__ Hbs,
                                                  const int* __restrict__ esrc,
                                                  const int* __restrict__ rowStart,
                                                  const float* __restrict__ dis,
                                                  const float* __restrict__ b,
                                                  const float* __restrict__ W3,
                                                  const float* __restrict__ b3,
                                                  float* __restrict__ colS,
                                                  float* __restrict__ outF,
                                                  int N) {
    int lane = threadIdx.x & 63;
    int c = lane & 7;
    int oct = lane >> 3;
    int ob = oct << 3;
    int wave = (blockIdx.x * 256 + threadIdx.x) >> 6;
    int g0 = wave * 8;
    if (g0 >= N) return;
    const char* hb = (const char*)Hbs + c * 16;

    int rb = rowStart[min(g0 + lane, N)];
    int Rq  = __shfl(rb, oct, 64);
    int Rq1 = __shfl(rb, oct + 1, 64);
    int n = g0 + oct;
    int nc = min(n, N - 1);

    float4 aL, aH;
    {
        uint4 sd = *(const uint4*)(hb + ((size_t)nc << 7));
        aL.x = BLO(sd.x); aL.y = BHI(sd.x); aL.z = BLO(sd.y); aL.w = BHI(sd.y);
        aH.x = BLO(sd.z); aH.y = BHI(sd.z); aH.z = BLO(sd.w); aH.w = BHI(sd.w);
    }
    GATHER_OCTET_BODY()

    float ds = dis[nc];
    float4 bL = ((const float4*)b)[2 * c];
    float4 bH = ((const float4*)b)[2 * c + 1];
    float4 vL, vH;
    vL.x = fmaxf(aL.x * ds + bL.x, 0.f);
    vL.y = fmaxf(aL.y * ds + bL.y, 0.f);
    vL.z = fmaxf(aL.z * ds + bL.z, 0.f);
    vL.w = fmaxf(aL.w * ds + bL.w, 0.f);
    vH.x = fmaxf(aH.x * ds + bH.x, 0.f);
    vH.y = fmaxf(aH.y * ds + bH.y, 0.f);
    vH.z = fmaxf(aH.z * ds + bH.z, 0.f);
    vH.w = fmaxf(aH.w * ds + bH.w, 0.f);

    float4 wL = ((const float4*)W3)[2 * c];
    float4 wH = ((const float4*)W3)[2 * c + 1];
    float t = vL.x * wL.x + vL.y * wL.y + vL.z * wL.z + vL.w * wL.w
            + vH.x * wH.x + vH.y * wH.y + vH.z * wH.z + vH.w * wH.w;
    t += __shfl_xor(t, 1, 64);
    t += __shfl_xor(t, 2, 64);
    t += __shfl_xor(t, 4, 64);
    if (c == 0 && n < N) {
        colS[n] = t * ds;
        outF[n] = t * ds * ds + b3[0];
    }
}

// layer-3 aggregation: stage block's colS values in LDS, per-node sum from LDS
__global__ __launch_bounds__(256) void k_gather1(const float* __restrict__ colS,
                                                 const int* __restrict__ esrc,
                                                 const int* __restrict__ rowStart,
                                                 const float* __restrict__ dis,
                                                 float* __restrict__ out, int N) {
    __shared__ float ls[G1CAP];
    int tid = threadIdx.x;
    int n0 = blockIdx.x * 256;
    int nEnd = min(n0 + 256, N);
    int r0 = rowStart[n0];
    int r1 = rowStart[nEnd];
    int cnt = r1 - r0;
    if (cnt <= G1CAP) {
        for (int i = tid; i < cnt; i += 256)
            ls[i] = colS[((unsigned)esrc[r0 + i]) >> 7];
        __syncthreads();
        int n = n0 + tid;
        if (n < N) {
            int a = rowStart[n] - r0, bnd = rowStart[n + 1] - r0;
            float acc = 0.0f;
            for (int e = a; e < bnd; ++e) acc += ls[e];
            out[n] += acc * dis[n];
        }
    } else {   // statistically unreachable fallback
        int n = n0 + tid;
        if (n < N) {
            int a = rowStart[n], bnd = rowStart[n + 1];
            float acc = 0.0f;
            for (int e = a; e < bnd; ++e) acc += colS[((unsigned)esrc[e]) >> 7];
            out[n] += acc * dis[n];
        }
    }
}

extern "C" void kernel_launch(void* const* d_in, const int* in_sizes, int n_in,
                              void* d_out, int out_size, void* d_ws, size_t ws_size,
                              hipStream_t stream) {
    const float* x  = (const float*)d_in[0];
    const int*   ei = (const int*)d_in[1];
    const float* W1 = (const float*)d_in[2];
    const float* b1 = (const float*)d_in[3];
    const float* W2 = (const float*)d_in[4];
    const float* b2 = (const float*)d_in[5];
    const float* W3 = (const float*)d_in[6];
    const float* b3 = (const float*)d_in[7];
    float* out = (float*)d_out;

    const int N = in_sizes[0] / IN_DIM;     // 100000
    const int E = in_sizes[1] / 2;          // 1600000
    const int* src = ei;
    const int* dst = ei + E;
    const int NC = (N + 255) >> 8;          // 391 coarse buckets
    const int NBLK = (E + EPB - 1) / EPB;   // 391 partition blocks

    // ---- workspace layout ----
    char* w = (char*)d_ws;
    auto alloc = [&](size_t bytes) {
        char* p = w;
        w += (bytes + 1023) & ~(size_t)1023;
        return p;
    };
    float*          dis        = (float*)alloc((size_t)N * 4);
    unsigned short* Hbs        = (unsigned short*)alloc((size_t)N * 64 * 2);
    unsigned short* Hb1        = (unsigned short*)alloc((size_t)N * 64 * 2);
    float*          colS       = (float*)alloc((size_t)N * 4);
    int*            rowStart   = (int*)alloc((size_t)(N + 1) * 4);
    int*            bktTotal   = (int*)alloc((size_t)MAXC * 4);
    int*            coarseStart= (int*)alloc((size_t)(MAXC + 1) * 4);
    int*            hmat       = (int*)alloc((size_t)MAXB * MAXC * 4);
    int*            esrc       = (int*)alloc((size_t)E * 4 + 1024);
    int*            tmp1       = (int*)alloc((size_t)E * 4);
    int*            ctr        = (int*)alloc(64);

    const int NB_N   = (N + 255) / 256;
    const int NB_MX  = (N + 63) / 64;                    // MFMA transform blocks
    const int NB_G8  = (((N + 7) / 8) * 64 + 255) / 256; // 8 nodes per wave
    const int NB_GMX = (N + 31) / 32;                    // 32 nodes per block

    // ---- deterministic partition (4 kernels; cscan folded into bktscan) ----
    k_hist2<<<NBLK, 256, 0, stream>>>(dst, hmat, ctr, E, NC);
    k_bktscan<<<NC, 512, 0, stream>>>(hmat, bktTotal, ctr, coarseStart, rowStart,
                                      NBLK, NC, N, E);
    k_part1<<<NBLK, 256, 0, stream>>>(src, dst, hmat, coarseStart, tmp1, E, NC);
    k_degplace<<<NC, DPT, 0, stream>>>(tmp1, coarseStart, dis, rowStart, esrc, N);

    // ---- layer 1 transform ----
    k_mmx<IN_DIM, float><<<NB_MX, 256, 0, stream>>>(x, W1, dis, Hbs, N);

    // ---- fused: layer-1 gather + layer-2 transform (Hbs -> Hb1, via LDS) ----
    k_gmx<<<NB_GMX, 256, 0, stream>>>(Hbs, esrc, rowStart, dis, b1, W2, Hb1, N);

    // ---- layer-2 gather fused with W3 dot ----
    k_gatherW3<<<NB_G8, 256, 0, stream>>>(Hb1, esrc, rowStart, dis, b2,
                                          W3, b3, colS, out, N);

    // ---- layer 3 aggregation ----
    k_gather1<<<NB_N, 256, 0, stream>>>(colS, esrc, rowStart, dis, out, N);
}